// Round 1
// baseline (116.072 us; speedup 1.0000x reference)
//
#include <hip/hip_runtime.h>
#include <math.h>

// Problem: x[N,D] f32, w[D,1] f32. a=sigmoid(x@w), b=cumsum(a) (increments <1 so
// idx=floor(b) is non-decreasing with steps in {0,1}). Each column i contributes
// to at most 2 output rows: main_val at idx[i], cross_val at idx[i]-1.
// Output row r = sum_{i: idx[i]==r} main[i]*x[i,:] + cross[s]*x[s,:] where s is
// the first i with idx[i]==r+1. Contiguous ranges found by binary search on idx.

__global__ void dot_sigmoid_kernel(const float* __restrict__ x,
                                   const float* __restrict__ w,
                                   float* __restrict__ a, int N, int D) {
  int lane = threadIdx.x & 63;
  int wave = threadIdx.x >> 6;
  int row = blockIdx.x * (blockDim.x >> 6) + wave;
  if (row >= N) return;
  const float4* xr = reinterpret_cast<const float4*>(x + (size_t)row * D);
  const float4* w4 = reinterpret_cast<const float4*>(w);
  float acc = 0.f;
  int nv = D >> 2;
  for (int j = lane; j < nv; j += 64) {
    float4 xv = xr[j];
    float4 wv = w4[j];
    acc = fmaf(xv.x, wv.x, acc);
    acc = fmaf(xv.y, wv.y, acc);
    acc = fmaf(xv.z, wv.z, acc);
    acc = fmaf(xv.w, wv.w, acc);
  }
#pragma unroll
  for (int off = 32; off > 0; off >>= 1) acc += __shfl_down(acc, off, 64);
  if (lane == 0) a[row] = 1.0f / (1.0f + expf(-acc));
}

// Single-block scan: 1024 threads x 8 elements. f64 accumulation so our b
// tracks the true sum at least as closely as the reference's f32 cumsum.
__global__ __launch_bounds__(1024) void scan_kernel(const float* __restrict__ a,
                                                    float* __restrict__ mainv,
                                                    float* __restrict__ crossv,
                                                    int* __restrict__ idxv, int N) {
  const int T = 1024;
  int t = threadIdx.x;
  int per = N / T;  // 8 for N=8192
  int base = t * per;
  double loc[16];
  double run = 0.0;
  for (int j = 0; j < per; ++j) {
    run += (double)a[base + j];
    loc[j] = run;
  }
  // inclusive scan of per-thread totals across the block
  double v = run;
  int lane = t & 63;
  int wid = t >> 6;  // 16 waves
  for (int off = 1; off < 64; off <<= 1) {
    double n = __shfl_up(v, off, 64);
    if (lane >= off) v += n;
  }
  __shared__ double wtot[16];
  __shared__ double woff[16];
  if (lane == 63) wtot[wid] = v;
  __syncthreads();
  if (t == 0) {
    double s = 0.0;
    for (int k2 = 0; k2 < 16; ++k2) { woff[k2] = s; s += wtot[k2]; }
  }
  __syncthreads();
  double pre = woff[wid] + (v - run);  // exclusive prefix before this chunk
  double prevbd = pre;
  for (int j = 0; j < per; ++j) {
    int i = base + j;
    double bd = pre + loc[j];
    float bf = (float)bd;
    float pf = (float)prevbd;
    int k = (int)floorf(bf);
    int kp = (int)floorf(pf);  // i==0 -> pre==0 -> kp==0, matches prev[0]=0
    float ai = a[i];
    float frac = bf - (float)k;
    bool same = (k == kp);
    mainv[i] = same ? ai : frac;
    crossv[i] = same ? 0.f : (ai - frac);
    idxv[i] = k;
    prevbd = bd;
  }
}

// One block per output row. idx[] is sorted; binary-search the range.
__global__ __launch_bounds__(256) void out_kernel(const float* __restrict__ x,
                                                  const float* __restrict__ mainv,
                                                  const float* __restrict__ crossv,
                                                  const int* __restrict__ idxv,
                                                  float* __restrict__ out, int N, int D) {
  int r = blockIdx.x;
  // s0 = first i with idx[i] >= r ; s1 = first i with idx[i] > r
  int lo = 0, hi = N;
  while (lo < hi) { int m = (lo + hi) >> 1; if (idxv[m] < r) lo = m + 1; else hi = m; }
  int s0 = lo;
  hi = N;
  while (lo < hi) { int m = (lo + hi) >> 1; if (idxv[m] <= r) lo = m + 1; else hi = m; }
  int s1 = lo;

  int c = threadIdx.x << 2;  // 256 threads * 4 floats = D
  float4 acc = make_float4(0.f, 0.f, 0.f, 0.f);
  for (int i = s0; i < s1; ++i) {
    float wgt = mainv[i];
    float4 xv = *reinterpret_cast<const float4*>(x + (size_t)i * D + c);
    acc.x = fmaf(wgt, xv.x, acc.x);
    acc.y = fmaf(wgt, xv.y, acc.y);
    acc.z = fmaf(wgt, xv.z, acc.z);
    acc.w = fmaf(wgt, xv.w, acc.w);
  }
  if (s1 < N) {  // first column of row r+1 crosses the boundary back into row r
    float wgt = crossv[s1];
    float4 xv = *reinterpret_cast<const float4*>(x + (size_t)s1 * D + c);
    acc.x = fmaf(wgt, xv.x, acc.x);
    acc.y = fmaf(wgt, xv.y, acc.y);
    acc.z = fmaf(wgt, xv.z, acc.z);
    acc.w = fmaf(wgt, xv.w, acc.w);
  }
  *reinterpret_cast<float4*>(out + (size_t)r * D + c) = acc;
}

extern "C" void kernel_launch(void* const* d_in, const int* in_sizes, int n_in,
                              void* d_out, int out_size, void* d_ws, size_t ws_size,
                              hipStream_t stream) {
  const float* x = (const float*)d_in[0];
  const float* w = (const float*)d_in[1];
  float* out = (float*)d_out;
  int D = in_sizes[1];      // 1024 (w is [D,1])
  int N = in_sizes[0] / D;  // 8192

  float* a = (float*)d_ws;
  float* mainv = a + N;
  float* crossv = mainv + N;
  int* idxv = (int*)(crossv + N);

  // Kernel 1: one wave per row dot product + sigmoid
  int waves_per_block = 4;  // 256 threads
  dim3 g1((N + waves_per_block - 1) / waves_per_block);
  hipLaunchKernelGGL(dot_sigmoid_kernel, g1, dim3(256), 0, stream, x, w, a, N, D);

  // Kernel 2: single-block scan -> idx/main/cross
  hipLaunchKernelGGL(scan_kernel, dim3(1), dim3(1024), 0, stream, a, mainv, crossv,
                     idxv, N);

  // Kernel 3: one block per output row
  hipLaunchKernelGGL(out_kernel, dim3(N), dim3(D / 4), 0, stream, x, mainv, crossv,
                     idxv, out, N, D);
}

// Round 2
// 102.986 us; speedup vs baseline: 1.1271x; 1.1271x over previous
//
#include <hip/hip_runtime.h>
#include <math.h>

// Problem: x[N,D] f32, w[D,1] f32. a=sigmoid(x@w) in (0,1), b=cumsum(a), so
// idx=floor(b) is non-decreasing with steps in {0,1}. Column i contributes
// main_val at row idx[i] and (on a crossing) cross_val at row idx[i]-1.
// Row r's column range is [rowptr[r], rowptr[r+1]); rowptr is built directly
// by the scan kernel (one scatter per crossing) — no binary search needed.

__global__ void dot_sigmoid_kernel(const float* __restrict__ x,
                                   const float* __restrict__ w,
                                   float* __restrict__ a, int N, int D) {
  int lane = threadIdx.x & 63;
  int wave = threadIdx.x >> 6;
  int row = blockIdx.x * (blockDim.x >> 6) + wave;
  if (row >= N) return;
  const float4* xr = reinterpret_cast<const float4*>(x + (size_t)row * D);
  const float4* w4 = reinterpret_cast<const float4*>(w);
  float acc = 0.f;
  int nv = D >> 2;  // 256
  for (int j = lane; j < nv; j += 64) {
    float4 xv = xr[j];
    float4 wv = w4[j];
    acc = fmaf(xv.x, wv.x, acc);
    acc = fmaf(xv.y, wv.y, acc);
    acc = fmaf(xv.z, wv.z, acc);
    acc = fmaf(xv.w, wv.w, acc);
  }
#pragma unroll
  for (int off = 32; off > 0; off >>= 1) acc += __shfl_down(acc, off, 64);
  if (lane == 0) a[row] = 1.0f / (1.0f + expf(-acc));
}

// Single-block scan: 1024 threads x 8 elements, f64 running sum (tighter than
// the reference's f32 cumsum). Emits mainv/crossv per column and rowptr[r] =
// first column of row r (N if row r is empty / past the end).
__global__ __launch_bounds__(1024) void scan_kernel(const float* __restrict__ a,
                                                    float* __restrict__ mainv,
                                                    float* __restrict__ crossv,
                                                    int* __restrict__ rowptr, int N) {
  __shared__ float sa[8192];
  __shared__ double wtot[16];
  __shared__ double woff[16];
  int t = threadIdx.x;
  // coalesced stage of a[] into LDS
  for (int k = t; k < N; k += 1024) sa[k] = a[k];
  // default rowptr: N (empty row)
  for (int k = t; k <= N; k += 1024) rowptr[k] = N;
  if (t == 0) rowptr[0] = 0;  // row 0 always starts at column 0
  __syncthreads();

  int per = N / 1024;  // 8
  int base = t * per;
  double loc[8];
  double run = 0.0;
#pragma unroll
  for (int j = 0; j < 8; ++j) {
    run += (double)sa[base + j];
    loc[j] = run;
  }
  // inclusive scan of per-thread totals: wave shuffle + cross-wave via LDS
  double v = run;
  int lane = t & 63;
  int wid = t >> 6;  // 16 waves
  for (int off = 1; off < 64; off <<= 1) {
    double n = __shfl_up(v, off, 64);
    if (lane >= off) v += n;
  }
  if (lane == 63) wtot[wid] = v;
  __syncthreads();
  if (t == 0) {
    double s = 0.0;
    for (int k2 = 0; k2 < 16; ++k2) { woff[k2] = s; s += wtot[k2]; }
  }
  __syncthreads();
  double pre = woff[wid] + (v - run);  // exclusive prefix before this chunk
  double prevbd = pre;
#pragma unroll
  for (int j = 0; j < 8; ++j) {
    int i = base + j;
    double bd = pre + loc[j];
    float bf = (float)bd;
    float pf = (float)prevbd;
    int k = (int)floorf(bf);
    int kp = (int)floorf(pf);  // i==0 -> pre==0 -> kp==0, matches prev[0]=0
    float ai = sa[i];
    float frac = bf - (float)k;
    bool same = (k == kp);
    mainv[i] = same ? ai : frac;
    crossv[i] = same ? 0.f : (ai - frac);
    if (!same) rowptr[k] = i;  // crossing: row k starts at column i (unique)
    prevbd = bd;
  }
}

// One block per output row; range comes from rowptr (2 uniform loads).
__global__ __launch_bounds__(256) void out_kernel(const float* __restrict__ x,
                                                  const float* __restrict__ mainv,
                                                  const float* __restrict__ crossv,
                                                  const int* __restrict__ rowptr,
                                                  float* __restrict__ out, int N, int D) {
  int r = blockIdx.x;
  int s0 = rowptr[r];
  int s1 = rowptr[r + 1];

  int c = threadIdx.x << 2;  // 256 threads * 4 floats = D
  float4 acc = make_float4(0.f, 0.f, 0.f, 0.f);
  for (int i = s0; i < s1; ++i) {
    float wgt = mainv[i];
    float4 xv = *reinterpret_cast<const float4*>(x + (size_t)i * D + c);
    acc.x = fmaf(wgt, xv.x, acc.x);
    acc.y = fmaf(wgt, xv.y, acc.y);
    acc.z = fmaf(wgt, xv.z, acc.z);
    acc.w = fmaf(wgt, xv.w, acc.w);
  }
  if (s1 < N) {  // first column of row r+1 crosses back into row r
    float wgt = crossv[s1];
    float4 xv = *reinterpret_cast<const float4*>(x + (size_t)s1 * D + c);
    acc.x = fmaf(wgt, xv.x, acc.x);
    acc.y = fmaf(wgt, xv.y, acc.y);
    acc.z = fmaf(wgt, xv.z, acc.z);
    acc.w = fmaf(wgt, xv.w, acc.w);
  }
  *reinterpret_cast<float4*>(out + (size_t)r * D + c) = acc;
}

extern "C" void kernel_launch(void* const* d_in, const int* in_sizes, int n_in,
                              void* d_out, int out_size, void* d_ws, size_t ws_size,
                              hipStream_t stream) {
  const float* x = (const float*)d_in[0];
  const float* w = (const float*)d_in[1];
  float* out = (float*)d_out;
  int D = in_sizes[1];      // 1024 (w is [D,1])
  int N = in_sizes[0] / D;  // 8192

  float* a = (float*)d_ws;
  float* mainv = a + N;
  float* crossv = mainv + N;
  int* rowptr = (int*)(crossv + N);  // N+1 entries

  // Kernel 1: one wave per row dot product + sigmoid
  int waves_per_block = 4;  // 256 threads
  dim3 g1((N + waves_per_block - 1) / waves_per_block);
  hipLaunchKernelGGL(dot_sigmoid_kernel, g1, dim3(256), 0, stream, x, w, a, N, D);

  // Kernel 2: single-block scan -> mainv/crossv/rowptr
  hipLaunchKernelGGL(scan_kernel, dim3(1), dim3(1024), 0, stream, a, mainv, crossv,
                     rowptr, N);

  // Kernel 3: one block per output row
  hipLaunchKernelGGL(out_kernel, dim3(N), dim3(D / 4), 0, stream, x, mainv, crossv,
                     rowptr, out, N, D);
}